// Round 1
// baseline (2571.069 us; speedup 1.0000x reference)
//
#include <hip/hip_runtime.h>
#include <hip/hip_bf16.h>
#include <stdint.h>

// ---------------------------------------------------------------------------
// getGRU: 32-frame GRU recurrence + output projection feedback + per-frame BN
// B=256, IN=1024, H=2048, 3H=6144, T=32
//
// Decomposition per frame t (A_cat = [inp(1024) | h(2048)] fp16, K=3072):
//   r,z  : A_cat @ BT_rz^T   (BT_rz[j][k] = k<1024 ? W_x[k][j] : W_h[k-1024][j], j in [0,4096))
//   xn   : inp  @ W_x[:,4096:]   (K=1024, BT_xn)
//   hn   : h    @ W_h[:,4096:]   (K=2048, BT_hn)
//   h'   = (1-z)*n + z*h,  n = tanh(xn + r*hn)   -- fused in GEMM epilogue
//   out  = h' @ W_d + b_d  -> d_out[t], and fp16 copy into A_cat inp slot
// Final: BatchNorm over batch dim per (t, feature).
// ---------------------------------------------------------------------------

typedef __attribute__((ext_vector_type(8))) _Float16 half8;
typedef __attribute__((ext_vector_type(4))) float f32x4;

#define GLB_CAST(p) ((const __attribute__((address_space(1))) void*)(p))
#define LDS_CAST(p) ((__attribute__((address_space(3))) void*)(p))

static __device__ __forceinline__ void gload_lds16(const void* g, void* l) {
  __builtin_amdgcn_global_load_lds(GLB_CAST(g), LDS_CAST(l), 16, 0, 0);
}

static __device__ __forceinline__ unsigned short f2h(float f) {
  _Float16 h = (_Float16)f;
  return __builtin_bit_cast(unsigned short, h);
}

// ---------------------------------------------------------------------------
// Tiled transpose + f32 -> f16 convert:
//   dst[j*dst_ld + k_off + k] = f16(src[k*src_ld + j0 + j])
// grid = (J/32, K/32), block = 256
// ---------------------------------------------------------------------------
__global__ __launch_bounds__(256) void transpose_conv(
    const float* __restrict__ src, int src_ld, int j0,
    unsigned short* __restrict__ dst, int dst_ld, int k_off)
{
  __shared__ float tile[32][33];
  const int kt = blockIdx.y * 32, jt = blockIdx.x * 32;
  const int tr = threadIdx.x >> 5, tc = threadIdx.x & 31;
#pragma unroll
  for (int r = 0; r < 4; r++) {
    int k = kt + tr + r * 8;
    tile[tr + r * 8][tc] = src[(size_t)k * src_ld + j0 + jt + tc];
  }
  __syncthreads();
#pragma unroll
  for (int r = 0; r < 4; r++) {
    int j = jt + tr + r * 8;
    dst[(size_t)j * dst_ld + k_off + kt + tc] = f2h(tile[tc][tr + r * 8]);
  }
}

// ---------------------------------------------------------------------------
// Init: A_cat buf0 = [f16(x) | 0], h_f32 buf0 = 0.  grid=256, block=256
// ---------------------------------------------------------------------------
__global__ __launch_bounds__(256) void init_kernel(
    const float* __restrict__ x, unsigned short* __restrict__ cat0,
    float* __restrict__ hf0)
{
  const int b = blockIdx.x, tid = threadIdx.x;
  for (int k = tid; k < 3072; k += 256)
    cat0[b * 3072 + k] = (k < 1024) ? f2h(x[b * 1024 + k]) : (unsigned short)0;
  for (int i = tid; i < 2048; i += 256)
    hf0[b * 2048 + i] = 0.f;
}

// ---------------------------------------------------------------------------
// Fused gates GEMM + GRU cell update.
// grid = (64, 4): c0 = bx*32 (n-section feature cols), r0 = by*64 (batch rows)
// block = 256 (4 waves), wave w owns rows [w*16, w*16+16)
// K-loop over 3072 in steps of 64; section 2 = xn for k<1024 else hn.
// ---------------------------------------------------------------------------
__global__ __launch_bounds__(256) void gates_kernel(
    const unsigned short* __restrict__ cat_in,  // [256][3072] f16
    const unsigned short* __restrict__ btrz,    // [4096][3072] f16
    const unsigned short* __restrict__ btxn,    // [2048][1024] f16
    const unsigned short* __restrict__ bthn,    // [2048][2048] f16
    const float* __restrict__ bx, const float* __restrict__ bh,
    const float* __restrict__ h_in, float* __restrict__ h_out,
    unsigned short* __restrict__ cat_out)       // h slot: cols [1024,3072)
{
  __shared__ __attribute__((aligned(16))) unsigned short a_lds[64 * 64];
  __shared__ __attribute__((aligned(16))) unsigned short b_lds[3][32 * 64];
  const int tid = threadIdx.x;
  const int w = tid >> 6, l = tid & 63;
  const int c0 = blockIdx.x * 32;
  const int r0 = blockIdx.y * 64;

  f32x4 accR[2] = {}, accZ[2] = {}, accX[2] = {}, accH[2] = {};

  const int bj = tid >> 3, bch = tid & 7;  // B staging: row, 16B-chunk

  for (int kk = 0; kk < 3072; kk += 64) {
    __syncthreads();
    // stage A tile [64 rows][64 k] : 2 rounds x 256 lanes x 16B
#pragma unroll
    for (int rnd = 0; rnd < 2; rnd++) {
      int flat = rnd * 256 + tid;
      int row = flat >> 3, ch = flat & 7;
      gload_lds16(cat_in + (size_t)(r0 + row) * 3072 + kk + ch * 8,
                  a_lds + flat * 8);
    }
    // stage B tiles [32 j][64 k] x 3 sections
    gload_lds16(btrz + (size_t)(c0 + bj) * 3072 + kk + bch * 8,
                b_lds[0] + tid * 8);
    gload_lds16(btrz + (size_t)(2048 + c0 + bj) * 3072 + kk + bch * 8,
                b_lds[1] + tid * 8);
    {
      const unsigned short* s2 = (kk < 1024)
          ? (btxn + (size_t)(c0 + bj) * 1024 + kk + bch * 8)
          : (bthn + (size_t)(c0 + bj) * 2048 + (kk - 1024) + bch * 8);
      gload_lds16(s2, b_lds[2] + tid * 8);
    }
    __syncthreads();

    const int arow = w * 16 + (l & 15);
    const int koff = (l >> 4) * 8;
#pragma unroll
    for (int kh = 0; kh < 2; kh++) {
      half8 a = *(const half8*)(a_lds + arow * 64 + kh * 32 + koff);
#pragma unroll
      for (int nt = 0; nt < 2; nt++) {
        const int brow = (nt * 16 + (l & 15)) * 64 + kh * 32 + koff;
        half8 b0 = *(const half8*)(b_lds[0] + brow);
        half8 b1 = *(const half8*)(b_lds[1] + brow);
        half8 b2 = *(const half8*)(b_lds[2] + brow);
        accR[nt] = __builtin_amdgcn_mfma_f32_16x16x32_f16(a, b0, accR[nt], 0, 0, 0);
        accZ[nt] = __builtin_amdgcn_mfma_f32_16x16x32_f16(a, b1, accZ[nt], 0, 0, 0);
        if (kk < 1024)
          accX[nt] = __builtin_amdgcn_mfma_f32_16x16x32_f16(a, b2, accX[nt], 0, 0, 0);
        else
          accH[nt] = __builtin_amdgcn_mfma_f32_16x16x32_f16(a, b2, accH[nt], 0, 0, 0);
      }
    }
  }

  // epilogue: GRU cell update (C/D layout: col = lane&15, row = (lane>>4)*4+i)
#pragma unroll
  for (int nt = 0; nt < 2; nt++) {
    const int j = c0 + nt * 16 + (l & 15);
    const float bR = bx[j] + bh[j];
    const float bZ = bx[2048 + j] + bh[2048 + j];
    const float bXn = bx[4096 + j];
    const float bHn = bh[4096 + j];
#pragma unroll
    for (int i = 0; i < 4; i++) {
      const int b = r0 + w * 16 + (l >> 4) * 4 + i;
      float r = 1.f / (1.f + __expf(-(accR[nt][i] + bR)));
      float z = 1.f / (1.f + __expf(-(accZ[nt][i] + bZ)));
      float n = tanhf(accX[nt][i] + bXn + r * (accH[nt][i] + bHn));
      float hp = h_in[b * 2048 + j];
      float hv = (1.f - z) * n + z * hp;
      h_out[b * 2048 + j] = hv;
      cat_out[b * 3072 + 1024 + j] = f2h(hv);
    }
  }
}

// ---------------------------------------------------------------------------
// Out projection: out = h' @ W_d + b_d ; writes f32 frame to d_out and f16
// copy into A_cat inp slot.  grid = (32, 4), block = 256.
// ---------------------------------------------------------------------------
__global__ __launch_bounds__(256) void outproj_kernel(
    unsigned short* cat,                       // same buffer read (h) + written (inp)
    const unsigned short* __restrict__ btd,    // [1024][2048] f16
    const float* __restrict__ bd,
    float* __restrict__ out)                   // [256][1024] (d_out + t*256*1024)
{
  __shared__ __attribute__((aligned(16))) unsigned short a_lds[64 * 64];
  __shared__ __attribute__((aligned(16))) unsigned short b_lds[32 * 64];
  const int tid = threadIdx.x;
  const int w = tid >> 6, l = tid & 63;
  const int c0 = blockIdx.x * 32;
  const int r0 = blockIdx.y * 64;

  f32x4 acc[2] = {};
  const int bj = tid >> 3, bch = tid & 7;

  for (int kk = 0; kk < 2048; kk += 64) {
    __syncthreads();
#pragma unroll
    for (int rnd = 0; rnd < 2; rnd++) {
      int flat = rnd * 256 + tid;
      int row = flat >> 3, ch = flat & 7;
      gload_lds16(cat + (size_t)(r0 + row) * 3072 + 1024 + kk + ch * 8,
                  a_lds + flat * 8);
    }
    gload_lds16(btd + (size_t)(c0 + bj) * 2048 + kk + bch * 8, b_lds + tid * 8);
    __syncthreads();

    const int arow = w * 16 + (l & 15);
    const int koff = (l >> 4) * 8;
#pragma unroll
    for (int kh = 0; kh < 2; kh++) {
      half8 a = *(const half8*)(a_lds + arow * 64 + kh * 32 + koff);
#pragma unroll
      for (int nt = 0; nt < 2; nt++) {
        half8 b = *(const half8*)(b_lds + (nt * 16 + (l & 15)) * 64 + kh * 32 + koff);
        acc[nt] = __builtin_amdgcn_mfma_f32_16x16x32_f16(a, b, acc[nt], 0, 0, 0);
      }
    }
  }

#pragma unroll
  for (int nt = 0; nt < 2; nt++) {
    const int j = c0 + nt * 16 + (l & 15);
    const float bb = bd[j];
#pragma unroll
    for (int i = 0; i < 4; i++) {
      const int b = r0 + w * 16 + (l >> 4) * 4 + i;
      float v = acc[nt][i] + bb;
      out[b * 1024 + j] = v;
      cat[b * 3072 + j] = f2h(v);
    }
  }
}

// ---------------------------------------------------------------------------
// BatchNorm over batch dim, in place on d_out.  grid = (32, 4), block = 256.
// ---------------------------------------------------------------------------
__global__ __launch_bounds__(256) void bn_kernel(
    float* __restrict__ O, const float* __restrict__ gamma,
    const float* __restrict__ beta)
{
  const int t = blockIdx.x, j = blockIdx.y * 256 + threadIdx.x;
  const size_t base = (size_t)t * 256 * 1024 + j;
  float s = 0.f, q = 0.f;
  for (int b = 0; b < 256; b++) {
    float v = O[base + (size_t)b * 1024];
    s += v; q += v * v;
  }
  const float mean = s * (1.f / 256.f);
  const float var = q * (1.f / 256.f) - mean * mean;
  const float inv = rsqrtf(var + 1e-5f);
  const float g = gamma[j] * inv, be = beta[j];
  for (int b = 0; b < 256; b++) {
    const size_t idx = base + (size_t)b * 1024;
    O[idx] = (O[idx] - mean) * g + be;
  }
}

// ---------------------------------------------------------------------------
extern "C" void kernel_launch(void* const* d_in, const int* in_sizes, int n_in,
                              void* d_out, int out_size, void* d_ws, size_t ws_size,
                              hipStream_t stream)
{
  (void)in_sizes; (void)n_in; (void)out_size; (void)ws_size;
  const float* x  = (const float*)d_in[0];
  const float* Wx = (const float*)d_in[1];
  const float* Wh = (const float*)d_in[2];
  const float* bx = (const float*)d_in[3];
  const float* bh = (const float*)d_in[4];
  const float* Wd = (const float*)d_in[5];
  const float* bd = (const float*)d_in[6];
  const float* gamma = (const float*)d_in[7];
  const float* beta  = (const float*)d_in[8];

  char* ws = (char*)d_ws;
  unsigned short* BT_rz = (unsigned short*)ws;             ws += (size_t)4096 * 3072 * 2;
  unsigned short* BT_xn = (unsigned short*)ws;             ws += (size_t)2048 * 1024 * 2;
  unsigned short* BT_hn = (unsigned short*)ws;             ws += (size_t)2048 * 2048 * 2;
  unsigned short* BT_d  = (unsigned short*)ws;             ws += (size_t)1024 * 2048 * 2;
  unsigned short* cat0  = (unsigned short*)ws;             ws += (size_t)256 * 3072 * 2;
  unsigned short* cat1  = (unsigned short*)ws;             ws += (size_t)256 * 3072 * 2;
  float* hf0 = (float*)ws;                                 ws += (size_t)256 * 2048 * 4;
  float* hf1 = (float*)ws;

  // --- setup: transposed f16 weight layouts --------------------------------
  transpose_conv<<<dim3(128, 32), 256, 0, stream>>>(Wx, 6144, 0,    BT_rz, 3072, 0);
  transpose_conv<<<dim3(128, 64), 256, 0, stream>>>(Wh, 6144, 0,    BT_rz, 3072, 1024);
  transpose_conv<<<dim3(64, 32),  256, 0, stream>>>(Wx, 6144, 4096, BT_xn, 1024, 0);
  transpose_conv<<<dim3(64, 64),  256, 0, stream>>>(Wh, 6144, 4096, BT_hn, 2048, 0);
  transpose_conv<<<dim3(32, 64),  256, 0, stream>>>(Wd, 1024, 0,    BT_d,  2048, 0);
  init_kernel<<<256, 256, 0, stream>>>(x, cat0, hf0);

  float* Of = (float*)d_out;
  for (int t = 0; t < 32; t++) {
    unsigned short* cin  = (t & 1) ? cat1 : cat0;
    unsigned short* cout = (t & 1) ? cat0 : cat1;
    const float* hin = (t & 1) ? hf1 : hf0;
    float* hout      = (t & 1) ? hf0 : hf1;
    gates_kernel<<<dim3(64, 4), 256, 0, stream>>>(
        cin, BT_rz, BT_xn, BT_hn, bx, bh, hin, hout, cout);
    outproj_kernel<<<dim3(32, 4), 256, 0, stream>>>(
        cout, BT_d, bd, Of + (size_t)t * 256 * 1024);
  }
  bn_kernel<<<dim3(32, 4), 256, 0, stream>>>(Of, gamma, beta);
}

// Round 2
// 1070.073 us; speedup vs baseline: 2.4027x; 2.4027x over previous
//
#include <hip/hip_runtime.h>
#include <hip/hip_bf16.h>
#include <stdint.h>

// ---------------------------------------------------------------------------
// getGRU restructured:
//   inp_t = h_t @ W_d + b_d  (t>=1)  =>  gx_t = h_t @ (W_d W_x) + bconst
//   => per-frame: ONE GEMM  [256 x 2048] @ WC^T, WC rows = [r|z|xn|hn] (8192)
//      WC[0:4096]   = (W_d W_x)[:, rz]^T + W_h[:, rz]^T
//      WC[4096:6144]= (W_d W_x)[:, n]^T
//      WC[6144:8192]= W_h[:, n]^T
//   out_t for all t: ONE batched GEMM  Hs[8192 x 2048] @ W_d + b_d, then BN.
// ---------------------------------------------------------------------------

typedef __attribute__((ext_vector_type(8))) _Float16 half8;
typedef __attribute__((ext_vector_type(4))) float f32x4;
typedef unsigned short u16;

#define GLB_CAST(p) ((const __attribute__((address_space(1))) void*)(p))
#define LDS_CAST(p) ((__attribute__((address_space(3))) void*)(p))

static __device__ __forceinline__ void gload_lds16(const void* g, void* l) {
  __builtin_amdgcn_global_load_lds(GLB_CAST(g), LDS_CAST(l), 16, 0, 0);
}
static __device__ __forceinline__ u16 f2h(float f) {
  _Float16 h = (_Float16)f;
  return __builtin_bit_cast(u16, h);
}
static __device__ __forceinline__ float h2f(u16 u) {
  _Float16 h = __builtin_bit_cast(_Float16, u);
  return (float)h;
}

// ---------------------------------------------------------------------------
// Tiled transpose + f32 -> f16:  dst[j*dst_ld + k] = f16(src[k*src_ld + j0 + j])
// grid = (J/32, K/32), block = 256
// ---------------------------------------------------------------------------
__global__ __launch_bounds__(256) void transpose_conv(
    const float* __restrict__ src, int src_ld, int j0,
    u16* __restrict__ dst, int dst_ld)
{
  __shared__ float tile[32][33];
  const int kt = blockIdx.y * 32, jt = blockIdx.x * 32;
  const int tr = threadIdx.x >> 5, tc = threadIdx.x & 31;
#pragma unroll
  for (int r = 0; r < 4; r++)
    tile[tr + r * 8][tc] = src[(size_t)(kt + tr + r * 8) * src_ld + j0 + jt + tc];
  __syncthreads();
#pragma unroll
  for (int r = 0; r < 4; r++)
    dst[(size_t)(jt + tr + r * 8) * dst_ld + kt + tc] = f2h(tile[tc][tr + r * 8]);
}

// f32 -> f16 elementwise, 4 per thread
__global__ __launch_bounds__(256) void convert_f2h(
    const float* __restrict__ src, u16* __restrict__ dst)
{
  const int i = (blockIdx.x * 256 + threadIdx.x) * 4;
  float4 v = *(const float4*)(src + i);
  dst[i + 0] = f2h(v.x); dst[i + 1] = f2h(v.y);
  dst[i + 2] = f2h(v.z); dst[i + 3] = f2h(v.w);
}

// bconst[j] = b_x[j] + sum_k b_d[k] * XT[j][k]   (j in [0,6144))
__global__ __launch_bounds__(256) void bconst_kernel(
    const float* __restrict__ bx, const float* __restrict__ bd,
    const u16* __restrict__ XT, float* __restrict__ bc)
{
  __shared__ float sbd[1024];
  const int tid = threadIdx.x;
  for (int i = tid; i < 1024; i += 256) sbd[i] = bd[i];
  __syncthreads();
  const int j = blockIdx.x * 256 + tid;
  const u16* row = XT + (size_t)j * 1024;
  float s = bx[j];
  for (int k = 0; k < 1024; k += 8) {
    half8 v = *(const half8*)(row + k);
#pragma unroll
    for (int u = 0; u < 8; u++) s += sbd[k + u] * (float)v[u];
  }
  bc[j] = s;
}

// ---------------------------------------------------------------------------
// Generic 128x128-tile GEMM, 512 threads (8 waves = 4 rw x 2 jw).
// C[m][n] = sum_k A[m][k]*B[n][k].  EPI 0: WC build (+HT for m<4096, u16 out)
//                                   EPI 1: f32 out + bias[n]
// ---------------------------------------------------------------------------
template <int EPI>
__global__ __launch_bounds__(512) void gemm128_kernel(
    const u16* __restrict__ A, int lda,
    const u16* __restrict__ Bm, int ldb,
    int K, int ldc,
    u16* __restrict__ Cw, const u16* __restrict__ HT,
    float* __restrict__ Cf, const float* __restrict__ bias)
{
  __shared__ __attribute__((aligned(16))) u16 a_lds[128 * 64];
  __shared__ __attribute__((aligned(16))) u16 b_lds[128 * 64];
  const int tid = threadIdx.x, w = tid >> 6, l = tid & 63;
  const int rw = w >> 1, jw = w & 1;
  const int n0 = blockIdx.x * 128, m0 = blockIdx.y * 128;

  f32x4 acc[2][4] = {};

  for (int kk = 0; kk < K; kk += 64) {
    __syncthreads();
#pragma unroll
    for (int rnd = 0; rnd < 2; rnd++) {
      int flat = rnd * 512 + tid;
      int row = flat >> 3, pch = flat & 7, gch = pch ^ (row & 7);
      gload_lds16(A + (size_t)(m0 + row) * lda + kk + gch * 8, a_lds + flat * 8);
    }
#pragma unroll
    for (int rnd = 0; rnd < 2; rnd++) {
      int flat = rnd * 512 + tid;
      int row = flat >> 3, pch = flat & 7, gch = pch ^ (row & 7);
      gload_lds16(Bm + (size_t)(n0 + row) * ldb + kk + gch * 8, b_lds + flat * 8);
    }
    __syncthreads();
#pragma unroll
    for (int kh = 0; kh < 2; kh++) {
      half8 a[2], b[4];
#pragma unroll
      for (int rf = 0; rf < 2; rf++) {
        int arow = rw * 32 + rf * 16 + (l & 15);
        int apch = (kh * 4 + (l >> 4)) ^ (arow & 7);
        a[rf] = *(const half8*)(a_lds + arow * 64 + apch * 8);
      }
#pragma unroll
      for (int nf = 0; nf < 4; nf++) {
        int brow = jw * 64 + nf * 16 + (l & 15);
        int bpch = (kh * 4 + (l >> 4)) ^ (brow & 7);
        b[nf] = *(const half8*)(b_lds + brow * 64 + bpch * 8);
      }
#pragma unroll
      for (int rf = 0; rf < 2; rf++)
#pragma unroll
        for (int nf = 0; nf < 4; nf++)
          acc[rf][nf] = __builtin_amdgcn_mfma_f32_16x16x32_f16(a[rf], b[nf], acc[rf][nf], 0, 0, 0);
    }
  }

#pragma unroll
  for (int rf = 0; rf < 2; rf++)
#pragma unroll
    for (int nf = 0; nf < 4; nf++) {
      const int n = n0 + jw * 64 + nf * 16 + (l & 15);
#pragma unroll
      for (int i = 0; i < 4; i++) {
        const int m = m0 + rw * 32 + rf * 16 + (l >> 4) * 4 + i;
        float v = acc[rf][nf][i];
        if (EPI == 0) {
          if (m < 4096) v += h2f(HT[(size_t)m * 2048 + n]);
          Cw[(size_t)m * ldc + n] = f2h(v);
        } else {
          Cf[(size_t)m * ldc + n] = v + bias[n];
        }
      }
    }
}

// ---------------------------------------------------------------------------
// Frame 0: gates from x @ W_x only (h=0).  grid (64,4), 512 thr.
// ---------------------------------------------------------------------------
__global__ __launch_bounds__(512) void frame0_kernel(
    const u16* __restrict__ x16, const u16* __restrict__ XT,
    const float* __restrict__ bx, const float* __restrict__ bh,
    float* __restrict__ h32out, u16* __restrict__ hout16)
{
  __shared__ __attribute__((aligned(16))) u16 a_lds[64 * 64];
  __shared__ __attribute__((aligned(16))) u16 b_lds[96 * 64];
  const int tid = threadIdx.x, w = tid >> 6, l = tid & 63;
  const int rw = w >> 1, jw = w & 1;
  const int jt = blockIdx.x, r0 = blockIdx.y * 64;
  f32x4 acc[3] = {};

  for (int kk = 0; kk < 1024; kk += 64) {
    __syncthreads();
    {
      int row = tid >> 3, pch = tid & 7, gch = pch ^ (row & 7);
      gload_lds16(x16 + (size_t)(r0 + row) * 1024 + kk + gch * 8, a_lds + tid * 8);
    }
#pragma unroll
    for (int rnd = 0; rnd < 2; rnd++) {
      int flat = rnd * 512 + tid;
      if (flat < 768) {
        int row = flat >> 3, pch = flat & 7, gch = pch ^ (row & 7);
        int s = row >> 5, jr = row & 31;
        gload_lds16(XT + (size_t)(s * 2048 + jt * 32 + jr) * 1024 + kk + gch * 8,
                    b_lds + flat * 8);
      }
    }
    __syncthreads();
#pragma unroll
    for (int kh = 0; kh < 2; kh++) {
      int arow = rw * 16 + (l & 15);
      int apch = (kh * 4 + (l >> 4)) ^ (arow & 7);
      half8 a = *(const half8*)(a_lds + arow * 64 + apch * 8);
#pragma unroll
      for (int s = 0; s < 3; s++) {
        int brow = s * 32 + jw * 16 + (l & 15);
        int bpch = (kh * 4 + (l >> 4)) ^ (brow & 7);
        half8 bf = *(const half8*)(b_lds + brow * 64 + bpch * 8);
        acc[s] = __builtin_amdgcn_mfma_f32_16x16x32_f16(a, bf, acc[s], 0, 0, 0);
      }
    }
  }

  const int j = jt * 32 + jw * 16 + (l & 15);
  const float cR = bx[j] + bh[j];
  const float cZ = bx[2048 + j] + bh[2048 + j];
  const float cX = bx[4096 + j];
  const float hn0 = bh[4096 + j];
#pragma unroll
  for (int i = 0; i < 4; i++) {
    const int b = r0 + rw * 16 + (l >> 4) * 4 + i;
    float r = 1.f / (1.f + __expf(-(acc[0][i] + cR)));
    float z = 1.f / (1.f + __expf(-(acc[1][i] + cZ)));
    float n = tanhf(acc[2][i] + cX + r * hn0);
    float hv = (1.f - z) * n;
    h32out[b * 2048 + j] = hv;
    hout16[b * 2048 + j] = f2h(hv);
  }
}

// ---------------------------------------------------------------------------
// Frames 1..31: gates = h @ WC^T (+consts), GRU update.  grid (64,4), 512 thr.
// ---------------------------------------------------------------------------
__global__ __launch_bounds__(512) void frame_kernel(
    const u16* __restrict__ hin16,   // Hs[t-1]  [256][2048]
    const u16* __restrict__ WC,      // [8192][2048]
    const float* __restrict__ bc,    // [6144]
    const float* __restrict__ bh,    // [6144]
    const float* __restrict__ h32in, float* __restrict__ h32out,
    u16* __restrict__ hout16)        // Hs[t]
{
  __shared__ __attribute__((aligned(16))) u16 a_lds[64 * 64];
  __shared__ __attribute__((aligned(16))) u16 b_lds[128 * 64];
  const int tid = threadIdx.x, w = tid >> 6, l = tid & 63;
  const int rw = w >> 1, jw = w & 1;
  const int jt = blockIdx.x, r0 = blockIdx.y * 64;
  f32x4 acc[4] = {};  // R, Z, Xn, Hn

  for (int kk = 0; kk < 2048; kk += 64) {
    __syncthreads();
    {
      int row = tid >> 3, pch = tid & 7, gch = pch ^ (row & 7);
      gload_lds16(hin16 + (size_t)(r0 + row) * 2048 + kk + gch * 8, a_lds + tid * 8);
    }
#pragma unroll
    for (int rnd = 0; rnd < 2; rnd++) {
      int flat = rnd * 512 + tid;
      int row = flat >> 3, pch = flat & 7, gch = pch ^ (row & 7);
      int s = row >> 5, jr = row & 31;
      gload_lds16(WC + (size_t)(s * 2048 + jt * 32 + jr) * 2048 + kk + gch * 8,
                  b_lds + flat * 8);
    }
    __syncthreads();
#pragma unroll
    for (int kh = 0; kh < 2; kh++) {
      int arow = rw * 16 + (l & 15);
      int apch = (kh * 4 + (l >> 4)) ^ (arow & 7);
      half8 a = *(const half8*)(a_lds + arow * 64 + apch * 8);
#pragma unroll
      for (int s = 0; s < 4; s++) {
        int brow = s * 32 + jw * 16 + (l & 15);
        int bpch = (kh * 4 + (l >> 4)) ^ (brow & 7);
        half8 bf = *(const half8*)(b_lds + brow * 64 + bpch * 8);
        acc[s] = __builtin_amdgcn_mfma_f32_16x16x32_f16(a, bf, acc[s], 0, 0, 0);
      }
    }
  }

  const int j = jt * 32 + jw * 16 + (l & 15);
  const float cR = bc[j] + bh[j];
  const float cZ = bc[2048 + j] + bh[2048 + j];
  const float cX = bc[4096 + j];
  const float cH = bh[4096 + j];
#pragma unroll
  for (int i = 0; i < 4; i++) {
    const int b = r0 + rw * 16 + (l >> 4) * 4 + i;
    float r = 1.f / (1.f + __expf(-(acc[0][i] + cR)));
    float z = 1.f / (1.f + __expf(-(acc[1][i] + cZ)));
    float n = tanhf(acc[2][i] + cX + r * (acc[3][i] + cH));
    float hp = h32in[b * 2048 + j];
    float hv = (1.f - z) * n + z * hp;
    h32out[b * 2048 + j] = hv;
    hout16[b * 2048 + j] = f2h(hv);
  }
}

// ---------------------------------------------------------------------------
// BatchNorm over batch dim, in place.  grid (32,4), block 256.
// ---------------------------------------------------------------------------
__global__ __launch_bounds__(256) void bn_kernel(
    float* __restrict__ O, const float* __restrict__ gamma,
    const float* __restrict__ beta)
{
  const int t = blockIdx.x, j = blockIdx.y * 256 + threadIdx.x;
  const size_t base = (size_t)t * 256 * 1024 + j;
  float s = 0.f, q = 0.f;
  for (int b = 0; b < 256; b++) {
    float v = O[base + (size_t)b * 1024];
    s += v; q += v * v;
  }
  const float mean = s * (1.f / 256.f);
  const float var = q * (1.f / 256.f) - mean * mean;
  const float inv = rsqrtf(var + 1e-5f);
  const float g = gamma[j] * inv, be = beta[j];
  for (int b = 0; b < 256; b++) {
    const size_t idx = base + (size_t)b * 1024;
    O[idx] = (O[idx] - mean) * g + be;
  }
}

// ---------------------------------------------------------------------------
extern "C" void kernel_launch(void* const* d_in, const int* in_sizes, int n_in,
                              void* d_out, int out_size, void* d_ws, size_t ws_size,
                              hipStream_t stream)
{
  (void)in_sizes; (void)n_in; (void)out_size; (void)ws_size;
  const float* x  = (const float*)d_in[0];
  const float* Wx = (const float*)d_in[1];
  const float* Wh = (const float*)d_in[2];
  const float* bx = (const float*)d_in[3];
  const float* bh = (const float*)d_in[4];
  const float* Wd = (const float*)d_in[5];
  const float* bd = (const float*)d_in[6];
  const float* gamma = (const float*)d_in[7];
  const float* beta  = (const float*)d_in[8];

  char* p = (char*)d_ws;
  u16* XT  = (u16*)p;  p += (size_t)6144 * 1024 * 2;   // W_x^T  [6144][1024]
  u16* WC  = (u16*)p;  p += (size_t)8192 * 2048 * 2;   // combined weights
  u16* DT  = (u16*)p;  p += (size_t)1024 * 2048 * 2;   // W_d^T  [1024][2048]
  float* h32a = (float*)p; p += (size_t)256 * 2048 * 4;
  float* h32b = (float*)p; p += (size_t)256 * 2048 * 4;
  u16* x16 = (u16*)p;  p += (size_t)256 * 1024 * 2;
  float* bc = (float*)p; p += (size_t)6144 * 4;
  // aliased region: HT+Wd16 (setup only) overlaid by Hs (frame0 onward)
  u16* Hs   = (u16*)p;                                  // [32][256][2048]
  u16* HT   = (u16*)p;                                  // [4096][2048]
  u16* Wd16 = (u16*)(p + (size_t)4096 * 2048 * 2);      // [2048][1024]

  const size_t BH = (size_t)256 * 2048;

  // --- setup -------------------------------------------------------------
  transpose_conv<<<dim3(192, 32), 256, 0, stream>>>(Wx, 6144, 0, XT, 1024);
  transpose_conv<<<dim3(128, 64), 256, 0, stream>>>(Wh, 6144, 0, HT, 2048);
  transpose_conv<<<dim3(64, 64), 256, 0, stream>>>(Wh, 6144, 4096,
                                                   WC + (size_t)6144 * 2048, 2048);
  transpose_conv<<<dim3(32, 64), 256, 0, stream>>>(Wd, 1024, 0, DT, 2048);
  convert_f2h<<<2048, 256, 0, stream>>>(Wd, Wd16);
  convert_f2h<<<256, 256, 0, stream>>>(x, x16);
  bconst_kernel<<<24, 256, 0, stream>>>(bx, bd, XT, bc);
  // WC[0:6144] = XT @ Wd16^T (+HT for rows<4096)
  gemm128_kernel<0><<<dim3(16, 48), 512, 0, stream>>>(
      XT, 1024, Wd16, 1024, 1024, 2048, WC, HT, nullptr, nullptr);

  // --- recurrence ----------------------------------------------------------
  frame0_kernel<<<dim3(64, 4), 512, 0, stream>>>(x16, XT, bx, bh, h32a, Hs);
  for (int t = 1; t < 32; t++) {
    const float* hin32 = (t & 1) ? h32a : h32b;
    float* hout32      = (t & 1) ? h32b : h32a;
    frame_kernel<<<dim3(64, 4), 512, 0, stream>>>(
        Hs + (size_t)(t - 1) * BH, WC, bc, bh, hin32, hout32, Hs + (size_t)t * BH);
  }

  // --- all 32 output frames in one GEMM + BN ------------------------------
  gemm128_kernel<1><<<dim3(8, 64), 512, 0, stream>>>(
      Hs, 2048, DT, 2048, 2048, 1024, nullptr, nullptr, (float*)d_out, bd);
  bn_kernel<<<dim3(32, 4), 256, 0, stream>>>((float*)d_out, gamma, beta);
}

// Round 3
// 999.390 us; speedup vs baseline: 2.5726x; 1.0707x over previous
//
#include <hip/hip_runtime.h>
#include <hip/hip_bf16.h>
#include <stdint.h>

// ---------------------------------------------------------------------------
// getGRU restructured:
//   inp_t = h_t @ W_d + b_d  (t>=1)  =>  gx_t = h_t @ (W_d W_x) + bconst
//   per-frame: ONE GEMM [256 x 2048] @ WC^T, WC rows = [r|z|xn|hn] (8192)
//   out_t for all t: ONE batched GEMM Hs[8192 x 2048] @ W_d + b_d, then BN.
// Round 3: 2-phase double-buffered LDS staging everywhere (1 block/CU had no
// overlap); gemm128 grid flipped so m-tile pins to XCD (A-panel L2 reuse).
// ---------------------------------------------------------------------------

typedef __attribute__((ext_vector_type(8))) _Float16 half8;
typedef __attribute__((ext_vector_type(4))) float f32x4;
typedef unsigned short u16;

#define GLB_CAST(p) ((const __attribute__((address_space(1))) void*)(p))
#define LDS_CAST(p) ((__attribute__((address_space(3))) void*)(p))

static __device__ __forceinline__ void gload_lds16(const void* g, void* l) {
  __builtin_amdgcn_global_load_lds(GLB_CAST(g), LDS_CAST(l), 16, 0, 0);
}
static __device__ __forceinline__ u16 f2h(float f) {
  _Float16 h = (_Float16)f;
  return __builtin_bit_cast(u16, h);
}
static __device__ __forceinline__ float h2f(u16 u) {
  _Float16 h = __builtin_bit_cast(_Float16, u);
  return (float)h;
}

// ---------------------------------------------------------------------------
// Tiled transpose + f32 -> f16:  dst[j*dst_ld + k] = f16(src[k*src_ld + j0 + j])
// ---------------------------------------------------------------------------
__global__ __launch_bounds__(256) void transpose_conv(
    const float* __restrict__ src, int src_ld, int j0,
    u16* __restrict__ dst, int dst_ld)
{
  __shared__ float tile[32][33];
  const int kt = blockIdx.y * 32, jt = blockIdx.x * 32;
  const int tr = threadIdx.x >> 5, tc = threadIdx.x & 31;
#pragma unroll
  for (int r = 0; r < 4; r++)
    tile[tr + r * 8][tc] = src[(size_t)(kt + tr + r * 8) * src_ld + j0 + jt + tc];
  __syncthreads();
#pragma unroll
  for (int r = 0; r < 4; r++)
    dst[(size_t)(jt + tr + r * 8) * dst_ld + kt + tc] = f2h(tile[tc][tr + r * 8]);
}

__global__ __launch_bounds__(256) void convert_f2h(
    const float* __restrict__ src, u16* __restrict__ dst)
{
  const int i = (blockIdx.x * 256 + threadIdx.x) * 4;
  float4 v = *(const float4*)(src + i);
  dst[i + 0] = f2h(v.x); dst[i + 1] = f2h(v.y);
  dst[i + 2] = f2h(v.z); dst[i + 3] = f2h(v.w);
}

// bconst[j] = b_x[j] + sum_k b_d[k] * XT[j][k]
__global__ __launch_bounds__(256) void bconst_kernel(
    const float* __restrict__ bx, const float* __restrict__ bd,
    const u16* __restrict__ XT, float* __restrict__ bc)
{
  __shared__ float sbd[1024];
  const int tid = threadIdx.x;
  for (int i = tid; i < 1024; i += 256) sbd[i] = bd[i];
  __syncthreads();
  const int j = blockIdx.x * 256 + tid;
  const u16* row = XT + (size_t)j * 1024;
  float s = bx[j];
  for (int k = 0; k < 1024; k += 8) {
    half8 v = *(const half8*)(row + k);
#pragma unroll
    for (int u = 0; u < 8; u++) s += sbd[k + u] * (float)v[u];
  }
  bc[j] = s;
}

// ---------------------------------------------------------------------------
// 128x128-tile GEMM, 512 threads, double-buffered 2-phase staging.
// grid = (M/128, N/128)  -- m-tile on x so XCD = m-tile%8 (A-panel L2 reuse).
// EPI 0: WC build (+HT for m<4096, u16 out).  EPI 1: f32 out + bias[n].
// ---------------------------------------------------------------------------
template <int EPI>
__global__ __launch_bounds__(512) void gemm128_kernel(
    const u16* __restrict__ A, int lda,
    const u16* __restrict__ Bm, int ldb,
    int K, int ldc,
    u16* __restrict__ Cw, const u16* __restrict__ HT,
    float* __restrict__ Cf, const float* __restrict__ bias)
{
  __shared__ __attribute__((aligned(16))) u16 a_lds[2][128 * 64];
  __shared__ __attribute__((aligned(16))) u16 b_lds[2][128 * 64];
  const int tid = threadIdx.x, w = tid >> 6, l = tid & 63;
  const int rw = w >> 1, jw = w & 1;
  const int m0 = blockIdx.x * 128, n0 = blockIdx.y * 128;

  f32x4 acc[2][4] = {};

  // staging source precompute: 2 rounds for A, 2 for B
  const u16* asrc[2];
  const u16* bsrc[2];
#pragma unroll
  for (int rnd = 0; rnd < 2; rnd++) {
    int flat = rnd * 512 + tid;
    int row = flat >> 3, gch = (flat & 7) ^ (row & 7);
    asrc[rnd] = A + (size_t)(m0 + row) * lda + gch * 8;
    bsrc[rnd] = Bm + (size_t)(n0 + row) * ldb + gch * 8;
  }

  auto stage = [&](int buf, int kk) {
#pragma unroll
    for (int rnd = 0; rnd < 2; rnd++) {
      int flat = rnd * 512 + tid;
      gload_lds16(asrc[rnd] + kk, a_lds[buf] + flat * 8);
      gload_lds16(bsrc[rnd] + kk, b_lds[buf] + flat * 8);
    }
  };

  stage(0, 0);
  __syncthreads();
  int cur = 0;
  const int nT = K >> 6;
  for (int t = 0; t < nT; ++t) {
    if (t + 1 < nT) stage(cur ^ 1, (t + 1) * 64);
#pragma unroll
    for (int kh = 0; kh < 2; kh++) {
      half8 a[2], b[4];
#pragma unroll
      for (int rf = 0; rf < 2; rf++) {
        int arow = rw * 32 + rf * 16 + (l & 15);
        int apch = (kh * 4 + (l >> 4)) ^ (arow & 7);
        a[rf] = *(const half8*)(a_lds[cur] + arow * 64 + apch * 8);
      }
#pragma unroll
      for (int nf = 0; nf < 4; nf++) {
        int brow = jw * 64 + nf * 16 + (l & 15);
        int bpch = (kh * 4 + (l >> 4)) ^ (brow & 7);
        b[nf] = *(const half8*)(b_lds[cur] + brow * 64 + bpch * 8);
      }
#pragma unroll
      for (int rf = 0; rf < 2; rf++)
#pragma unroll
        for (int nf = 0; nf < 4; nf++)
          acc[rf][nf] = __builtin_amdgcn_mfma_f32_16x16x32_f16(a[rf], b[nf], acc[rf][nf], 0, 0, 0);
    }
    __syncthreads();
    cur ^= 1;
  }

#pragma unroll
  for (int rf = 0; rf < 2; rf++)
#pragma unroll
    for (int nf = 0; nf < 4; nf++) {
      const int n = n0 + jw * 64 + nf * 16 + (l & 15);
#pragma unroll
      for (int i = 0; i < 4; i++) {
        const int m = m0 + rw * 32 + rf * 16 + (l >> 4) * 4 + i;
        float v = acc[rf][nf][i];
        if (EPI == 0) {
          if (m < 4096) v += h2f(HT[(size_t)m * 2048 + n]);
          Cw[(size_t)m * ldc + n] = f2h(v);
        } else {
          Cf[(size_t)m * ldc + n] = v + bias[n];
        }
      }
    }
}

// ---------------------------------------------------------------------------
// Frame 0: gates from x @ W_x only (h=0).  grid (64,4), 512 thr, dbuf.
// ---------------------------------------------------------------------------
__global__ __launch_bounds__(512) void frame0_kernel(
    const u16* __restrict__ x16, const u16* __restrict__ XT,
    const float* __restrict__ bx, const float* __restrict__ bh,
    float* __restrict__ h32out, u16* __restrict__ hout16)
{
  __shared__ __attribute__((aligned(16))) u16 a_lds[2][64 * 64];
  __shared__ __attribute__((aligned(16))) u16 b_lds[2][96 * 64];
  const int tid = threadIdx.x, w = tid >> 6, l = tid & 63;
  const int rw = w >> 1, jw = w & 1;
  const int jt = blockIdx.x, r0 = blockIdx.y * 64;
  f32x4 acc[3] = {};

  const int ar = tid >> 3;
  const int agch = (tid & 7) ^ (ar & 7);
  const u16* asrc = x16 + (size_t)(r0 + ar) * 1024 + agch * 8;
  const u16* bsrc[2];
#pragma unroll
  for (int rnd = 0; rnd < 2; rnd++) {
    int flat = rnd * 512 + tid;
    int row = flat >> 3, gch = (flat & 7) ^ (row & 7);
    int s = row >> 5, jr = row & 31;
    bsrc[rnd] = XT + (size_t)(s * 2048 + jt * 32 + jr) * 1024 + gch * 8;
  }

  auto stage = [&](int buf, int kk) {
    gload_lds16(asrc + kk, a_lds[buf] + tid * 8);
    gload_lds16(bsrc[0] + kk, b_lds[buf] + tid * 8);
    if (512 + tid < 768)
      gload_lds16(bsrc[1] + kk, b_lds[buf] + (512 + tid) * 8);
  };

  stage(0, 0);
  __syncthreads();
  int cur = 0;
  for (int t = 0; t < 16; ++t) {
    if (t < 15) stage(cur ^ 1, (t + 1) * 64);
    const int arow = rw * 16 + (l & 15);
#pragma unroll
    for (int kh = 0; kh < 2; kh++) {
      int apch = (kh * 4 + (l >> 4)) ^ (arow & 7);
      half8 a = *(const half8*)(a_lds[cur] + arow * 64 + apch * 8);
#pragma unroll
      for (int s = 0; s < 3; s++) {
        int brow = s * 32 + jw * 16 + (l & 15);
        int bpch = (kh * 4 + (l >> 4)) ^ (brow & 7);
        half8 bf = *(const half8*)(b_lds[cur] + brow * 64 + bpch * 8);
        acc[s] = __builtin_amdgcn_mfma_f32_16x16x32_f16(a, bf, acc[s], 0, 0, 0);
      }
    }
    __syncthreads();
    cur ^= 1;
  }

  const int j = jt * 32 + jw * 16 + (l & 15);
  const float cR = bx[j] + bh[j];
  const float cZ = bx[2048 + j] + bh[2048 + j];
  const float cX = bx[4096 + j];
  const float hn0 = bh[4096 + j];
#pragma unroll
  for (int i = 0; i < 4; i++) {
    const int b = r0 + rw * 16 + (l >> 4) * 4 + i;
    float r = 1.f / (1.f + __expf(-(acc[0][i] + cR)));
    float z = 1.f / (1.f + __expf(-(acc[1][i] + cZ)));
    float n = tanhf(acc[2][i] + cX + r * hn0);
    float hv = (1.f - z) * n;
    h32out[b * 2048 + j] = hv;
    hout16[b * 2048 + j] = f2h(hv);
  }
}

// ---------------------------------------------------------------------------
// Frames 1..31: gates = h @ WC^T (+consts), GRU update.  grid (64,4), dbuf.
// ---------------------------------------------------------------------------
__global__ __launch_bounds__(512) void frame_kernel(
    const u16* __restrict__ hin16,   // Hs[t-1]  [256][2048]
    const u16* __restrict__ WC,      // [8192][2048]
    const float* __restrict__ bc, const float* __restrict__ bh,
    const float* __restrict__ h32in, float* __restrict__ h32out,
    u16* __restrict__ hout16)        // Hs[t]
{
  __shared__ __attribute__((aligned(16))) u16 a_lds[2][64 * 64];
  __shared__ __attribute__((aligned(16))) u16 b_lds[2][128 * 64];
  const int tid = threadIdx.x, w = tid >> 6, l = tid & 63;
  const int rw = w >> 1, jw = w & 1;
  const int jt = blockIdx.x, r0 = blockIdx.y * 64;
  f32x4 acc[4] = {};  // R, Z, Xn, Hn

  const int ar = tid >> 3;
  const int agch = (tid & 7) ^ (ar & 7);
  const u16* asrc = hin16 + (size_t)(r0 + ar) * 2048 + agch * 8;
  const u16* bsrc[2];
#pragma unroll
  for (int rnd = 0; rnd < 2; rnd++) {
    int flat = rnd * 512 + tid;
    int row = flat >> 3, gch = (flat & 7) ^ (row & 7);
    int s = row >> 5, jr = row & 31;
    bsrc[rnd] = WC + (size_t)(s * 2048 + jt * 32 + jr) * 2048 + gch * 8;
  }

  auto stage = [&](int buf, int kk) {
    gload_lds16(asrc + kk, a_lds[buf] + tid * 8);
    gload_lds16(bsrc[0] + kk, b_lds[buf] + tid * 8);
    gload_lds16(bsrc[1] + kk, b_lds[buf] + (512 + tid) * 8);
  };

  stage(0, 0);
  __syncthreads();
  int cur = 0;
  for (int t = 0; t < 32; ++t) {
    if (t < 31) stage(cur ^ 1, (t + 1) * 64);
    const int arow = rw * 16 + (l & 15);
#pragma unroll
    for (int kh = 0; kh < 2; kh++) {
      int apch = (kh * 4 + (l >> 4)) ^ (arow & 7);
      half8 a = *(const half8*)(a_lds[cur] + arow * 64 + apch * 8);
#pragma unroll
      for (int s = 0; s < 4; s++) {
        int brow = s * 32 + jw * 16 + (l & 15);
        int bpch = (kh * 4 + (l >> 4)) ^ (brow & 7);
        half8 bf = *(const half8*)(b_lds[cur] + brow * 64 + bpch * 8);
        acc[s] = __builtin_amdgcn_mfma_f32_16x16x32_f16(a, bf, acc[s], 0, 0, 0);
      }
    }
    __syncthreads();
    cur ^= 1;
  }

  const int j = jt * 32 + jw * 16 + (l & 15);
  const float cR = bc[j] + bh[j];
  const float cZ = bc[2048 + j] + bh[2048 + j];
  const float cX = bc[4096 + j];
  const float cH = bh[4096 + j];
#pragma unroll
  for (int i = 0; i < 4; i++) {
    const int b = r0 + rw * 16 + (l >> 4) * 4 + i;
    float r = 1.f / (1.f + __expf(-(acc[0][i] + cR)));
    float z = 1.f / (1.f + __expf(-(acc[1][i] + cZ)));
    float n = tanhf(acc[2][i] + cX + r * (acc[3][i] + cH));
    float hp = h32in[b * 2048 + j];
    float hv = (1.f - z) * n + z * hp;
    h32out[b * 2048 + j] = hv;
    hout16[b * 2048 + j] = f2h(hv);
  }
}

// ---------------------------------------------------------------------------
// BatchNorm over batch dim, in place.  grid (32,4), block 256.
// ---------------------------------------------------------------------------
__global__ __launch_bounds__(256) void bn_kernel(
    float* __restrict__ O, const float* __restrict__ gamma,
    const float* __restrict__ beta)
{
  const int t = blockIdx.x, j = blockIdx.y * 256 + threadIdx.x;
  const size_t base = (size_t)t * 256 * 1024 + j;
  float s = 0.f, q = 0.f;
  for (int b = 0; b < 256; b++) {
    float v = O[base + (size_t)b * 1024];
    s += v; q += v * v;
  }
  const float mean = s * (1.f / 256.f);
  const float var = q * (1.f / 256.f) - mean * mean;
  const float inv = rsqrtf(var + 1e-5f);
  const float g = gamma[j] * inv, be = beta[j];
  for (int b = 0; b < 256; b++) {
    const size_t idx = base + (size_t)b * 1024;
    O[idx] = (O[idx] - mean) * g + be;
  }
}

// ---------------------------------------------------------------------------
extern "C" void kernel_launch(void* const* d_in, const int* in_sizes, int n_in,
                              void* d_out, int out_size, void* d_ws, size_t ws_size,
                              hipStream_t stream)
{
  (void)in_sizes; (void)n_in; (void)out_size; (void)ws_size;
  const float* x  = (const float*)d_in[0];
  const float* Wx = (const float*)d_in[1];
  const float* Wh = (const float*)d_in[2];
  const float* bx = (const float*)d_in[3];
  const float* bh = (const float*)d_in[4];
  const float* Wd = (const float*)d_in[5];
  const float* bd = (const float*)d_in[6];
  const float* gamma = (const float*)d_in[7];
  const float* beta  = (const float*)d_in[8];

  char* p = (char*)d_ws;
  u16* XT  = (u16*)p;  p += (size_t)6144 * 1024 * 2;   // W_x^T  [6144][1024]
  u16* WC  = (u16*)p;  p += (size_t)8192 * 2048 * 2;   // combined weights
  u16* DT  = (u16*)p;  p += (size_t)1024 * 2048 * 2;   // W_d^T  [1024][2048]
  float* h32a = (float*)p; p += (size_t)256 * 2048 * 4;
  float* h32b = (float*)p; p += (size_t)256 * 2048 * 4;
  u16* x16 = (u16*)p;  p += (size_t)256 * 1024 * 2;
  float* bc = (float*)p; p += (size_t)6144 * 4;
  // aliased region: HT+Wd16 (setup only) overlaid by Hs (frame0 onward)
  u16* Hs   = (u16*)p;                                  // [32][256][2048]
  u16* HT   = (u16*)p;                                  // [4096][2048]
  u16* Wd16 = (u16*)(p + (size_t)4096 * 2048 * 2);      // [2048][1024]

  const size_t BH = (size_t)256 * 2048;

  // --- setup ---------------------------------------------------------------
  transpose_conv<<<dim3(192, 32), 256, 0, stream>>>(Wx, 6144, 0, XT, 1024);
  transpose_conv<<<dim3(128, 64), 256, 0, stream>>>(Wh, 6144, 0, HT, 2048);
  transpose_conv<<<dim3(64, 64), 256, 0, stream>>>(Wh, 6144, 4096,
                                                   WC + (size_t)6144 * 2048, 2048);
  transpose_conv<<<dim3(32, 64), 256, 0, stream>>>(Wd, 1024, 0, DT, 2048);
  convert_f2h<<<2048, 256, 0, stream>>>(Wd, Wd16);
  convert_f2h<<<256, 256, 0, stream>>>(x, x16);
  bconst_kernel<<<24, 256, 0, stream>>>(bx, bd, XT, bc);
  // WC[0:6144] = XT @ Wd16^T (+HT for rows<4096); grid = (Mtiles, Ntiles)
  gemm128_kernel<0><<<dim3(48, 16), 512, 0, stream>>>(
      XT, 1024, Wd16, 1024, 1024, 2048, WC, HT, nullptr, nullptr);

  // --- recurrence ----------------------------------------------------------
  frame0_kernel<<<dim3(64, 4), 512, 0, stream>>>(x16, XT, bx, bh, h32a, Hs);
  for (int t = 1; t < 32; t++) {
    const float* hin32 = (t & 1) ? h32a : h32b;
    float* hout32      = (t & 1) ? h32b : h32a;
    frame_kernel<<<dim3(64, 4), 512, 0, stream>>>(
        Hs + (size_t)(t - 1) * BH, WC, bc, bh, hin32, hout32, Hs + (size_t)t * BH);
  }

  // --- all 32 output frames in one GEMM + BN -------------------------------
  gemm128_kernel<1><<<dim3(64, 8), 512, 0, stream>>>(
      Hs, 2048, DT, 2048, 2048, 1024, nullptr, nullptr, (float*)d_out, bd);
  bn_kernel<<<dim3(32, 4), 256, 0, stream>>>((float*)d_out, gamma, beta);
}

// Round 4
// 810.732 us; speedup vs baseline: 3.1713x; 1.2327x over previous
//
#include <hip/hip_runtime.h>
#include <hip/hip_bf16.h>
#include <stdint.h>

// ---------------------------------------------------------------------------
// getGRU restructured:
//   inp_t = h_t @ W_d + b_d  (t>=1)  =>  gx_t = h_t @ (W_d W_x) + bconst
//   per-frame: ONE GEMM [256 x 2048] @ WC^T, WC rows = [r|z|xn|hn] (8192)
//   out_t for all t: ONE batched GEMM Hs[8192 x 2048] @ W_d + b_d, then BN.
// Round 4: frame_kernel = 2rw x 2jw x 2kw wave split (48 KB LDS-reads/step/CU,
// was 80), 4-buffer pipelined staging with counted vmcnt(6) + raw s_barrier
// (loads stay in flight across barriers), setprio around MFMA, kw-reduction
// via LDS at end.  gemm128 = 256-thr 4x4-frag single-buffer (multi-block
// overlap) with m-fastest grid (XCD L2 reuse).
// ---------------------------------------------------------------------------

typedef __attribute__((ext_vector_type(8))) _Float16 half8;
typedef __attribute__((ext_vector_type(4))) float f32x4;
typedef unsigned short u16;

#define GLB_CAST(p) ((const __attribute__((address_space(1))) void*)(p))
#define LDS_CAST(p) ((__attribute__((address_space(3))) void*)(p))

static __device__ __forceinline__ void gload_lds16(const void* g, void* l) {
  __builtin_amdgcn_global_load_lds(GLB_CAST(g), LDS_CAST(l), 16, 0, 0);
}
static __device__ __forceinline__ u16 f2h(float f) {
  _Float16 h = (_Float16)f;
  return __builtin_bit_cast(u16, h);
}
static __device__ __forceinline__ float h2f(u16 u) {
  _Float16 h = __builtin_bit_cast(_Float16, u);
  return (float)h;
}

// ---------------------------------------------------------------------------
// Tiled transpose + f32 -> f16:  dst[j*dst_ld + k] = f16(src[k*src_ld + j0 + j])
// ---------------------------------------------------------------------------
__global__ __launch_bounds__(256) void transpose_conv(
    const float* __restrict__ src, int src_ld, int j0,
    u16* __restrict__ dst, int dst_ld)
{
  __shared__ float tile[32][33];
  const int kt = blockIdx.y * 32, jt = blockIdx.x * 32;
  const int tr = threadIdx.x >> 5, tc = threadIdx.x & 31;
#pragma unroll
  for (int r = 0; r < 4; r++)
    tile[tr + r * 8][tc] = src[(size_t)(kt + tr + r * 8) * src_ld + j0 + jt + tc];
  __syncthreads();
#pragma unroll
  for (int r = 0; r < 4; r++)
    dst[(size_t)(jt + tr + r * 8) * dst_ld + kt + tc] = f2h(tile[tc][tr + r * 8]);
}

__global__ __launch_bounds__(256) void convert_f2h(
    const float* __restrict__ src, u16* __restrict__ dst)
{
  const int i = (blockIdx.x * 256 + threadIdx.x) * 4;
  float4 v = *(const float4*)(src + i);
  dst[i + 0] = f2h(v.x); dst[i + 1] = f2h(v.y);
  dst[i + 2] = f2h(v.z); dst[i + 3] = f2h(v.w);
}

// bconst[j] = b_x[j] + sum_k b_d[k] * XT[j][k]
__global__ __launch_bounds__(256) void bconst_kernel(
    const float* __restrict__ bx, const float* __restrict__ bd,
    const u16* __restrict__ XT, float* __restrict__ bc)
{
  __shared__ float sbd[1024];
  const int tid = threadIdx.x;
  for (int i = tid; i < 1024; i += 256) sbd[i] = bd[i];
  __syncthreads();
  const int j = blockIdx.x * 256 + tid;
  const u16* row = XT + (size_t)j * 1024;
  float s = bx[j];
  for (int k = 0; k < 1024; k += 8) {
    half8 v = *(const half8*)(row + k);
#pragma unroll
    for (int u = 0; u < 8; u++) s += sbd[k + u] * (float)v[u];
  }
  bc[j] = s;
}

// ---------------------------------------------------------------------------
// 128x128-tile GEMM, 256 threads (4 waves = 2rw x 2jw), 4x4 frags/wave,
// single-buffered (32 KB -> multi-block/CU overlap).  grid = (M/128, N/128):
// m-tile on x so the n-blocks sharing an A-panel land on one XCD.
// EPI 0: WC build (+HT add for m<4096, u16 out).  EPI 1: f32 out + bias[n].
// ---------------------------------------------------------------------------
template <int EPI>
__global__ __launch_bounds__(256) void gemm128_kernel(
    const u16* __restrict__ A, int lda,
    const u16* __restrict__ Bm, int ldb,
    int K, int ldc,
    u16* __restrict__ Cw, const u16* __restrict__ HT,
    float* __restrict__ Cf, const float* __restrict__ bias)
{
  __shared__ __attribute__((aligned(16))) u16 a_lds[128 * 64];
  __shared__ __attribute__((aligned(16))) u16 b_lds[128 * 64];
  const int tid = threadIdx.x, w = tid >> 6, l = tid & 63;
  const int rw = w >> 1, jw = w & 1;
  const int m0 = blockIdx.x * 128, n0 = blockIdx.y * 128;

  f32x4 acc[4][4] = {};

  for (int kk = 0; kk < K; kk += 64) {
    __syncthreads();
#pragma unroll
    for (int rnd = 0; rnd < 4; rnd++) {
      int flat = rnd * 256 + tid;
      int row = flat >> 3, gch = (flat & 7) ^ (row & 7);
      gload_lds16(A + (size_t)(m0 + row) * lda + kk + gch * 8, a_lds + flat * 8);
      gload_lds16(Bm + (size_t)(n0 + row) * ldb + kk + gch * 8, b_lds + flat * 8);
    }
    __syncthreads();
#pragma unroll
    for (int kh = 0; kh < 2; kh++) {
      const int koff = kh * 4 + (l >> 4);
      half8 a[4], b[4];
#pragma unroll
      for (int mf = 0; mf < 4; mf++) {
        int arow = rw * 64 + mf * 16 + (l & 15);
        a[mf] = *(const half8*)(a_lds + (arow * 8 + (koff ^ (arow & 7))) * 8);
      }
#pragma unroll
      for (int nf = 0; nf < 4; nf++) {
        int brow = jw * 64 + nf * 16 + (l & 15);
        b[nf] = *(const half8*)(b_lds + (brow * 8 + (koff ^ (brow & 7))) * 8);
      }
#pragma unroll
      for (int mf = 0; mf < 4; mf++)
#pragma unroll
        for (int nf = 0; nf < 4; nf++)
          acc[mf][nf] = __builtin_amdgcn_mfma_f32_16x16x32_f16(a[mf], b[nf], acc[mf][nf], 0, 0, 0);
    }
  }

#pragma unroll
  for (int mf = 0; mf < 4; mf++)
#pragma unroll
    for (int nf = 0; nf < 4; nf++) {
      const int n = n0 + jw * 64 + nf * 16 + (l & 15);
#pragma unroll
      for (int i = 0; i < 4; i++) {
        const int m = m0 + rw * 64 + mf * 16 + (l >> 4) * 4 + i;
        float v = acc[mf][nf][i];
        if (EPI == 0) {
          if (m < 4096) v += h2f(HT[(size_t)m * 2048 + n]);
          Cw[(size_t)m * ldc + n] = f2h(v);
        } else {
          Cf[(size_t)m * ldc + n] = v + bias[n];
        }
      }
    }
}

// ---------------------------------------------------------------------------
// Frame 0: gates from x @ W_x only (h=0).  grid (64,4), 512 thr, dbuf.
// ---------------------------------------------------------------------------
__global__ __launch_bounds__(512) void frame0_kernel(
    const u16* __restrict__ x16, const u16* __restrict__ XT,
    const float* __restrict__ bx, const float* __restrict__ bh,
    float* __restrict__ h32out, u16* __restrict__ hout16)
{
  __shared__ __attribute__((aligned(16))) u16 a_lds[2][64 * 64];
  __shared__ __attribute__((aligned(16))) u16 b_lds[2][96 * 64];
  const int tid = threadIdx.x, w = tid >> 6, l = tid & 63;
  const int rw = w >> 1, jw = w & 1;
  const int jt = blockIdx.x, r0 = blockIdx.y * 64;
  f32x4 acc[3] = {};

  const int ar = tid >> 3;
  const int agch = (tid & 7) ^ (ar & 7);
  const u16* asrc = x16 + (size_t)(r0 + ar) * 1024 + agch * 8;
  const u16* bsrc0;
  const u16* bsrc1;
  {
    int row0 = tid >> 3, gch0 = (tid & 7) ^ (row0 & 7);
    bsrc0 = XT + (size_t)((row0 >> 5) * 2048 + jt * 32 + (row0 & 31)) * 1024 + gch0 * 8;
    int flat = 512 + tid;
    int row1 = flat >> 3, gch1 = (flat & 7) ^ (row1 & 7);
    bsrc1 = XT + (size_t)((row1 >> 5) * 2048 + jt * 32 + (row1 & 31)) * 1024 + gch1 * 8;
  }

  auto stage = [&](int buf, int kk) {
    gload_lds16(asrc + kk, a_lds[buf] + tid * 8);
    gload_lds16(bsrc0 + kk, b_lds[buf] + tid * 8);
    if (512 + tid < 768)
      gload_lds16(bsrc1 + kk, b_lds[buf] + (512 + tid) * 8);
  };

  stage(0, 0);
  __syncthreads();
  int cur = 0;
  for (int t = 0; t < 16; ++t) {
    if (t < 15) stage(cur ^ 1, (t + 1) * 64);
    const int arow = rw * 16 + (l & 15);
#pragma unroll
    for (int kh = 0; kh < 2; kh++) {
      int apch = (kh * 4 + (l >> 4)) ^ (arow & 7);
      half8 a = *(const half8*)(a_lds[cur] + arow * 64 + apch * 8);
#pragma unroll
      for (int s = 0; s < 3; s++) {
        int brow = s * 32 + jw * 16 + (l & 15);
        int bpch = (kh * 4 + (l >> 4)) ^ (brow & 7);
        half8 bf = *(const half8*)(b_lds[cur] + brow * 64 + bpch * 8);
        acc[s] = __builtin_amdgcn_mfma_f32_16x16x32_f16(a, bf, acc[s], 0, 0, 0);
      }
    }
    __syncthreads();
    cur ^= 1;
  }

  const int j = jt * 32 + jw * 16 + (l & 15);
  const float cR = bx[j] + bh[j];
  const float cZ = bx[2048 + j] + bh[2048 + j];
  const float cX = bx[4096 + j];
  const float hn0 = bh[4096 + j];
#pragma unroll
  for (int i = 0; i < 4; i++) {
    const int b = r0 + rw * 16 + (l >> 4) * 4 + i;
    float r = 1.f / (1.f + __expf(-(acc[0][i] + cR)));
    float z = 1.f / (1.f + __expf(-(acc[1][i] + cZ)));
    float n = tanhf(acc[2][i] + cX + r * hn0);
    float hv = (1.f - z) * n;
    h32out[b * 2048 + j] = hv;
    hout16[b * 2048 + j] = f2h(hv);
  }
}

// ---------------------------------------------------------------------------
// Frames 1..31: gates = h @ WC^T (+consts), GRU update.
// grid (64,4), 512 thr = 8 waves = 2rw x 2jw x 2kw.
// Per wave per K-step: 2 A + 4 B ds_read_b128, 8 MFMA (kh = kw slice only).
// 4-buffer pipeline, prefetch distance 2, counted vmcnt, raw s_barrier.
// End: kw=1 partials -> LDS, kw=0 reduce + GRU epilogue.
// ---------------------------------------------------------------------------
__global__ __launch_bounds__(512) void frame_kernel(
    const u16* __restrict__ hin16,   // Hs[t-1]  [256][2048]
    const u16* __restrict__ WC,      // [8192][2048]
    const float* __restrict__ bc, const float* __restrict__ bh,
    const float* __restrict__ h32in, float* __restrict__ h32out,
    u16* __restrict__ hout16)        // Hs[t]
{
  __shared__ __attribute__((aligned(16))) u16 a_lds[4][64 * 64];   // 32 KB
  __shared__ __attribute__((aligned(16))) u16 b_lds[4][128 * 64];  // 64 KB
  const int tid = threadIdx.x, w = tid >> 6, l = tid & 63;
  const int rw = (w >> 2) & 1, jw = (w >> 1) & 1, kw = w & 1;
  const int jt = blockIdx.x, r0 = blockIdx.y * 64;

  f32x4 acc[2][4] = {};  // [mf][sec]  sec: R,Z,Xn,Hn

  const int ar = tid >> 3, agch = (tid & 7) ^ (ar & 7);
  const u16* asrc = hin16 + (size_t)(r0 + ar) * 2048 + agch * 8;
  const u16* bsrc0;
  const u16* bsrc1;
  {
    int row0 = tid >> 3, gch0 = (tid & 7) ^ (row0 & 7);
    bsrc0 = WC + (size_t)((row0 >> 5) * 2048 + jt * 32 + (row0 & 31)) * 2048 + gch0 * 8;
    int flat = 512 + tid;
    int row1 = flat >> 3, gch1 = (flat & 7) ^ (row1 & 7);
    bsrc1 = WC + (size_t)((row1 >> 5) * 2048 + jt * 32 + (row1 & 31)) * 2048 + gch1 * 8;
  }

  // 3 gload_lds per thread per stage (vmcnt counting relies on this)
  auto stage = [&](int buf, int step) {
    const int kk = step * 64;
    gload_lds16(asrc + kk, a_lds[buf] + tid * 8);
    gload_lds16(bsrc0 + kk, b_lds[buf] + tid * 8);
    gload_lds16(bsrc1 + kk, b_lds[buf] + (512 + tid) * 8);
  };

  auto compute = [&](int buf) {
    const int koff = kw * 4 + (l >> 4);
    half8 a[2], b[4];
#pragma unroll
    for (int mf = 0; mf < 2; mf++) {
      int arow = rw * 32 + mf * 16 + (l & 15);
      a[mf] = *(const half8*)(a_lds[buf] + (arow * 8 + (koff ^ (arow & 7))) * 8);
    }
#pragma unroll
    for (int s = 0; s < 4; s++) {
      int brow = s * 32 + jw * 16 + (l & 15);
      b[s] = *(const half8*)(b_lds[buf] + (brow * 8 + (koff ^ (brow & 7))) * 8);
    }
    __builtin_amdgcn_s_setprio(1);
#pragma unroll
    for (int mf = 0; mf < 2; mf++)
#pragma unroll
      for (int s = 0; s < 4; s++)
        acc[mf][s] = __builtin_amdgcn_mfma_f32_16x16x32_f16(a[mf], b[s], acc[mf][s], 0, 0, 0);
    __builtin_amdgcn_s_setprio(0);
  };

  stage(0, 0);
  stage(1, 1);
#pragma unroll 1
  for (int t = 0; t < 30; ++t) {
    stage((t + 2) & 3, t + 2);
    // wait stage(t) landed (9 outstanding -> 6), then barrier: all waves' t-data in
    asm volatile("s_waitcnt vmcnt(6)\n\ts_barrier" ::: "memory");
    compute(t & 3);
  }
  asm volatile("s_waitcnt vmcnt(3)\n\ts_barrier" ::: "memory");
  compute(30 & 3);
  asm volatile("s_waitcnt vmcnt(0)\n\ts_barrier" ::: "memory");
  compute(31 & 3);

  // ---- kw reduction + GRU epilogue ----
  __syncthreads();                       // all LDS reads of staged bufs done
  float* xch = (float*)&a_lds[0][0];     // 32 KB exchange region
  const int wid2 = rw * 2 + jw;
  if (kw == 1) {
#pragma unroll
    for (int mf = 0; mf < 2; mf++)
#pragma unroll
      for (int s = 0; s < 4; s++)
        *(f32x4*)(xch + ((((wid2 * 2 + mf) * 4 + s) * 64 + l) * 4)) = acc[mf][s];
  }
  __syncthreads();
  if (kw == 0) {
#pragma unroll
    for (int mf = 0; mf < 2; mf++)
#pragma unroll
      for (int s = 0; s < 4; s++) {
        f32x4 p = *(const f32x4*)(xch + ((((wid2 * 2 + mf) * 4 + s) * 64 + l) * 4));
        acc[mf][s] += p;
      }
    const int j = jt * 32 + jw * 16 + (l & 15);
    const float cR = bc[j] + bh[j];
    const float cZ = bc[2048 + j] + bh[2048 + j];
    const float cX = bc[4096 + j];
    const float cH = bh[4096 + j];
#pragma unroll
    for (int mf = 0; mf < 2; mf++)
#pragma unroll
      for (int i = 0; i < 4; i++) {
        const int b = r0 + rw * 32 + mf * 16 + (l >> 4) * 4 + i;
        float r = 1.f / (1.f + __expf(-(acc[mf][0][i] + cR)));
        float z = 1.f / (1.f + __expf(-(acc[mf][1][i] + cZ)));
        float n = tanhf(acc[mf][2][i] + cX + r * (acc[mf][3][i] + cH));
        float hp = h32in[b * 2048 + j];
        float hv = (1.f - z) * n + z * hp;
        h32out[b * 2048 + j] = hv;
        hout16[b * 2048 + j] = f2h(hv);
      }
  }
}

// ---------------------------------------------------------------------------
// BatchNorm over batch dim, in place.  grid (32,4), block 256.
// ---------------------------------------------------------------------------
__global__ __launch_bounds__(256) void bn_kernel(
    float* __restrict__ O, const float* __restrict__ gamma,
    const float* __restrict__ beta)
{
  const int t = blockIdx.x, j = blockIdx.y * 256 + threadIdx.x;
  const size_t base = (size_t)t * 256 * 1024 + j;
  float s = 0.f, q = 0.f;
  for (int b = 0; b < 256; b++) {
    float v = O[base + (size_t)b * 1024];
    s += v; q += v * v;
  }
  const float mean = s * (1.f / 256.f);
  const float var = q * (1.f / 256.f) - mean * mean;
  const float inv = rsqrtf(var + 1e-5f);
  const float g = gamma[j] * inv, be = beta[j];
  for (int b = 0; b < 256; b++) {
    const size_t idx = base + (size_t)b * 1024;
    O[idx] = (O[idx] - mean) * g + be;
  }
}

// ---------------------------------------------------------------------------
extern "C" void kernel_launch(void* const* d_in, const int* in_sizes, int n_in,
                              void* d_out, int out_size, void* d_ws, size_t ws_size,
                              hipStream_t stream)
{
  (void)in_sizes; (void)n_in; (void)out_size; (void)ws_size;
  const float* x  = (const float*)d_in[0];
  const float* Wx = (const float*)d_in[1];
  const float* Wh = (const float*)d_in[2];
  const float* bx = (const float*)d_in[3];
  const float* bh = (const float*)d_in[4];
  const float* Wd = (const float*)d_in[5];
  const float* bd = (const float*)d_in[6];
  const float* gamma = (const float*)d_in[7];
  const float* beta  = (const float*)d_in[8];

  char* p = (char*)d_ws;
  u16* XT  = (u16*)p;  p += (size_t)6144 * 1024 * 2;   // W_x^T  [6144][1024]
  u16* WC  = (u16*)p;  p += (size_t)8192 * 2048 * 2;   // combined weights
  u16* DT  = (u16*)p;  p += (size_t)1024 * 2048 * 2;   // W_d^T  [1024][2048]
  float* h32a = (float*)p; p += (size_t)256 * 2048 * 4;
  float* h32b = (float*)p; p += (size_t)256 * 2048 * 4;
  u16* x16 = (u16*)p;  p += (size_t)256 * 1024 * 2;
  float* bc = (float*)p; p += (size_t)6144 * 4;
  // aliased region: HT+Wd16 (setup only) overlaid by Hs (frame0 onward)
  u16* Hs   = (u16*)p;                                  // [32][256][2048]
  u16* HT   = (u16*)p;                                  // [4096][2048]
  u16* Wd16 = (u16*)(p + (size_t)4096 * 2048 * 2);      // [2048][1024]

  const size_t BH = (size_t)256 * 2048;

  // --- setup ---------------------------------------------------------------
  transpose_conv<<<dim3(192, 32), 256, 0, stream>>>(Wx, 6144, 0, XT, 1024);
  transpose_conv<<<dim3(128, 64), 256, 0, stream>>>(Wh, 6144, 0, HT, 2048);
  transpose_conv<<<dim3(64, 64), 256, 0, stream>>>(Wh, 6144, 4096,
                                                   WC + (size_t)6144 * 2048, 2048);
  transpose_conv<<<dim3(32, 64), 256, 0, stream>>>(Wd, 1024, 0, DT, 2048);
  convert_f2h<<<2048, 256, 0, stream>>>(Wd, Wd16);
  convert_f2h<<<256, 256, 0, stream>>>(x, x16);
  bconst_kernel<<<24, 256, 0, stream>>>(bx, bd, XT, bc);
  // WC[0:6144] = XT @ Wd16^T (+HT for rows<4096); grid = (Mtiles, Ntiles)
  gemm128_kernel<0><<<dim3(48, 16), 256, 0, stream>>>(
      XT, 1024, Wd16, 1024, 1024, 2048, WC, HT, nullptr, nullptr);

  // --- recurrence ----------------------------------------------------------
  frame0_kernel<<<dim3(64, 4), 512, 0, stream>>>(x16, XT, bx, bh, h32a, Hs);
  for (int t = 1; t < 32; t++) {
    const float* hin32 = (t & 1) ? h32a : h32b;
    float* hout32      = (t & 1) ? h32b : h32a;
    frame_kernel<<<dim3(64, 4), 512, 0, stream>>>(
        Hs + (size_t)(t - 1) * BH, WC, bc, bh, hin32, hout32, Hs + (size_t)t * BH);
  }

  // --- all 32 output frames in one GEMM + BN -------------------------------
  gemm128_kernel<1><<<dim3(64, 8), 256, 0, stream>>>(
      Hs, 2048, DT, 2048, 2048, 1024, nullptr, nullptr, (float*)d_out, bd);
  bn_kernel<<<dim3(32, 4), 256, 0, stream>>>((float*)d_out, gamma, beta);
}